// Round 7
// baseline (271.129 us; speedup 1.0000x reference)
//
#include <hip/hip_runtime.h>
#include <stdint.h>

#define NP 1024
#define NV 49408
#define ND 512
// A,B packed: [row][hi(512)|lo(512)] bf16 -> physical K=1024 (2048 B/row).
// Logical K=1536, 3-term split, BK=64 -> 24 K-tiles:
//   t 0-7:  ah*bh   t 8-15: al*bh   t 16-23: ah*bl
//   A phys byte = (t & 15) * 128
//   B phys byte = ((t & 7) + (t >= 16 ? 8 : 0)) * 128
#define NT 24
#define NI 12

typedef __attribute__((ext_vector_type(8))) __bf16 bf16x8;
typedef __attribute__((ext_vector_type(4))) float f32x4;

__device__ inline unsigned long long pack_sv(float s, unsigned v) {
  unsigned u = __float_as_uint(s);
  u = (u & 0x80000000u) ? ~u : (u | 0x80000000u);  // orderable map
  return ((unsigned long long)u << 32) | (unsigned long long)v;
}

// Split each f32 row into bf16 hi/lo halves, layout [row][hi(512)|lo(512)];
// optionally emit exact f32 sum of squares per row.
__global__ __launch_bounds__(256) void pack_rows_k(const float* __restrict__ src,
                                                   __bf16* __restrict__ dst,
                                                   float* __restrict__ sumsq,
                                                   int nrows) {
  int lane = threadIdx.x & 63;
  int row = blockIdx.x * 4 + (threadIdx.x >> 6);
  if (row >= nrows) return;
  const float* r = src + (size_t)row * ND + lane * 8;
  float4 x0 = *(const float4*)r;
  float4 x1 = *(const float4*)(r + 4);
  float xs[8] = {x0.x, x0.y, x0.z, x0.w, x1.x, x1.y, x1.z, x1.w};
  bf16x8 hi, lo;
  float ss = 0.f;
#pragma unroll
  for (int j = 0; j < 8; ++j) {
    float x = xs[j];
    ss += x * x;
    __bf16 h = (__bf16)x;
    hi[j] = h;
    lo[j] = (__bf16)(x - (float)h);   // exact residual, then RTNE to bf16
  }
  __bf16* drow = dst + (size_t)row * 1024 + lane * 8;
  *(bf16x8*)drow = hi;
  *(bf16x8*)(drow + 512) = lo;
  if (sumsq != nullptr) {
#pragma unroll
    for (int m = 1; m < 64; m <<= 1) ss += __shfl_xor(ss, m);
    if (lane == 0) sumsq[row] = ss;
  }
}

// ---- 256x256, BK=64, 8-wave (2Mx4N), m201-style 8-phase dbuf pipeline ------
// LDS 128 KiB: buf b at b*65536: A-half h (128 rows x 64 cols bf16, 16 KB) at
// +h*16384; B-half h at +32768+h*16384. 16B-slot XOR swizzle within each row:
// slot' = slot ^ (row & 7) (involution; fragment reads hit the 2-lane/bank
// floor). Stage: linear LDS dest + inverse-swizzled global source (rule #21).

__device__ __attribute__((always_inline)) static inline
void gll16(const char* src, char* dst) {
  __builtin_amdgcn_global_load_lds(
      (const __attribute__((address_space(1))) void*)src,
      (__attribute__((address_space(3))) void*)dst, 16, 0, 0);
}

// one half-tile = 128 rows x 128 B; thread covers rows tid>>3 and +64
__device__ __attribute__((always_inline)) static inline
void stage_half(const char* src, char* dst) {
  gll16(src, dst);
  gll16(src + 131072, dst + 8192);
}

template <int OFF>
__device__ __attribute__((always_inline)) static inline
void read_a(bf16x8 (&a)[4][2], const char* aP0, const char* aP1) {
#pragma unroll
  for (int mm = 0; mm < 4; ++mm) {
    a[mm][0] = *(const bf16x8*)(aP0 + OFF + mm * 2048);
    a[mm][1] = *(const bf16x8*)(aP1 + OFF + mm * 2048);
  }
}

template <int OFF>
__device__ __attribute__((always_inline)) static inline
void read_b(bf16x8 (&b)[2][2], const char* bP0, const char* bP1) {
#pragma unroll
  for (int nn = 0; nn < 2; ++nn) {
    b[nn][0] = *(const bf16x8*)(bP0 + OFF + nn * 2048);
    b[nn][1] = *(const bf16x8*)(bP1 + OFF + nn * 2048);
  }
}

template <int MB, int NB>
__device__ __attribute__((always_inline)) static inline
void mfma16(f32x4 (&acc)[8][4], const bf16x8 (&a)[4][2], const bf16x8 (&b)[2][2]) {
  __builtin_amdgcn_s_setprio(1);
#pragma unroll
  for (int mm = 0; mm < 4; ++mm)
#pragma unroll
    for (int nn = 0; nn < 2; ++nn)
#pragma unroll
      for (int kk = 0; kk < 2; ++kk)
        acc[MB + mm][NB + nn] = __builtin_amdgcn_mfma_f32_16x16x32_bf16(
            a[mm][kk], b[nn][kk], acc[MB + mm][NB + nn], 0, 0, 0);
  __builtin_amdgcn_s_setprio(0);
}

#define FENCE asm volatile("" ::: "memory")
#define BAR1  do { FENCE; __builtin_amdgcn_s_barrier(); FENCE; } while (0)
#define ENDP  do { FENCE; __builtin_amdgcn_s_barrier(); FENCE; } while (0)
#define VMC4  asm volatile("s_waitcnt vmcnt(4)" ::: "memory")

__global__ __launch_bounds__(512, 2) void gemm_argmin_k(const __bf16* __restrict__ A,
                                                        const __bf16* __restrict__ B,
                                                        const float* __restrict__ b2,
                                                        unsigned long long* __restrict__ best) {
  __shared__ __align__(128) char lds[131072];
  const int tid = threadIdx.x;
  const int lane = tid & 63;
  const int wid = tid >> 6;   // 0..7
  const int wm = wid >> 2;    // 2 wave-rows (128 rows each)
  const int wn = wid & 3;     // 4 wave-cols (64 cols each)

  // bijective XCD-chunk swizzle, nwg = 772 = 8*96 + 4 (m204 formula):
  const int d = blockIdx.x;
  const int xcd = d & 7;
  const int wg = (xcd < 4 ? xcd * 97 : 388 + (xcd - 4) * 96) + (d >> 3);
  const int bm = (wg & 3) * 256;   // 4 M-blocks per B-panel, same XCD
  const int bn = (wg >> 2) * 256;

  const int r = lane & 15, g = lane >> 4;
  const int sl = (g ^ (r & 7)) * 16;
  const int offA = wm * 16384 + r * 128 + sl;
  const int offB = 32768 + (wn >> 1) * 16384 + (wn & 1) * 8192 + r * 128 + sl;
  const char* aP0 = (const char*)lds + offA;
  const char* aP1 = (const char*)lds + (offA ^ 64);   // kk=1: slot bit2 toggle
  const char* bP0 = (const char*)lds + offB;
  const char* bP1 = (const char*)lds + (offB ^ 64);

  // stage side: thread covers row tid>>3 (+64 / +128-half), slot (tid&7),
  // inverse-swizzled global column slot:
  const int srow = tid >> 3;
  const int sc = (tid & 7) ^ (srow & 7);
  const char* srcA = (const char*)A + (size_t)(bm + srow) * 2048 + sc * 16;
  const char* srcB = (const char*)B + (size_t)(bn + srow) * 2048 + sc * 16;
  char* st = (char*)lds + tid * 16;

  f32x4 acc[8][4] = {};
  bf16x8 a[4][2], b0[2][2], b1[2][2];

  auto aByte = [](int t) { return (t & 15) * 128; };
  auto bByte = [](int t) { return ((t & 7) + (t >= 16 ? 8 : 0)) * 128; };

  // prologue: buf0 all 4 halves (tile 0) + buf1 B halves (tile 1)
  stage_half(srcA + aByte(0),          st + 0);        // b0.A0
  stage_half(srcA + aByte(0) + 262144, st + 16384);    // b0.A1
  stage_half(srcB + bByte(0),          st + 32768);    // b0.B0
  stage_half(srcB + bByte(0) + 262144, st + 49152);    // b0.B1
  stage_half(srcB + bByte(1),          st + 98304);    // b1.B0
  stage_half(srcB + bByte(1) + 262144, st + 114688);   // b1.B1
  VMC4;            // buf0 fully resident; buf1.B in flight
  BAR1;

  // per iter: T0=2it (buf0), T1=2it+1 (buf1); stages:
  //  P1:b1.A0(T1) P2:b1.A1(T1) P3:b0.B0(T0+2) P4:b0.B1 [vmcnt4]
  //  P5:b0.A0(T0+2) P6:b0.A1 P7:b1.B0(T1+2) P8:b1.B1 [vmcnt4]
#pragma unroll 1
  for (int it = 0; it < NI; ++it) {
    const int T1 = 2 * it + 1;
    int S0 = 2 * it + 2; if (S0 >= NT) S0 -= NT;   // tail wrap: dead re-stage
    int S1 = 2 * it + 3; if (S1 >= NT) S1 -= NT;
    // P1 (buf0, quad m0n0)
    read_a<0>(a, aP0, aP1);
    read_b<0>(b0, bP0, bP1);
    stage_half(srcA + aByte(T1), st + 65536);
    BAR1; mfma16<0, 0>(acc, a, b0); ENDP;
    // P2 (m0n1)
    read_b<4096>(b1, bP0, bP1);
    stage_half(srcA + aByte(T1) + 262144, st + 81920);
    BAR1; mfma16<0, 2>(acc, a, b1); ENDP;
    // P3 (m1n1)
    read_a<8192>(a, aP0, aP1);
    stage_half(srcB + bByte(S0), st + 32768);
    BAR1; mfma16<4, 2>(acc, a, b1); ENDP;
    // P4 (m1n0)  [no reads]
    stage_half(srcB + bByte(S0) + 262144, st + 49152);
    BAR1; mfma16<4, 0>(acc, a, b0); VMC4; ENDP;
    // P5 (buf1, m0n0)
    read_a<65536>(a, aP0, aP1);
    read_b<65536>(b0, bP0, bP1);
    stage_half(srcA + aByte(S0), st + 0);
    BAR1; mfma16<0, 0>(acc, a, b0); ENDP;
    // P6 (m0n1)
    read_b<69632>(b1, bP0, bP1);
    stage_half(srcA + aByte(S0) + 262144, st + 16384);
    BAR1; mfma16<0, 2>(acc, a, b1); ENDP;
    // P7 (m1n1)
    read_a<73728>(a, aP0, aP1);
    stage_half(srcB + bByte(S1), st + 98304);
    BAR1; mfma16<4, 2>(acc, a, b1); ENDP;
    // P8 (m1n0)
    stage_half(srcB + bByte(S1) + 262144, st + 114688);
    BAR1; mfma16<4, 0>(acc, a, b0); VMC4; ENDP;
  }

  // epilogue: fused argmin. C/D map: col = lane&15, row = (lane>>4)*4 + reg.
  float bb[4];
#pragma unroll
  for (int n = 0; n < 4; ++n) bb[n] = b2[bn + wn * 64 + n * 16 + r];
#pragma unroll
  for (int m = 0; m < 8; ++m) {
#pragma unroll
    for (int reg = 0; reg < 4; ++reg) {
      unsigned long long pk = ~0ull;
#pragma unroll
      for (int n = 0; n < 4; ++n) {
        float s = bb[n] - 2.0f * acc[m][n][reg];
        unsigned long long cand = pack_sv(s, (unsigned)(bn + wn * 64 + n * 16 + r));
        pk = (cand < pk) ? cand : pk;
      }
#pragma unroll
      for (int msk = 1; msk < 16; msk <<= 1) {
        unsigned long long o = __shfl_xor(pk, msk);
        pk = (o < pk) ? o : pk;
      }
      if (r == 0) atomicMin(&best[bm + wm * 128 + m * 16 + g * 4 + reg], pk);
    }
  }
}

// Fallback (small ws): exact fp32 squared distance, fused argmin.
__global__ __launch_bounds__(256) void naive_argmin_k(const float* __restrict__ A,
                                                      const float* __restrict__ B,
                                                      unsigned long long* __restrict__ best) {
  __shared__ float arow[ND];
  int p = blockIdx.y;
  unsigned v = blockIdx.x * 256 + threadIdx.x;
  for (int i = threadIdx.x; i < ND; i += 256) arow[i] = A[(size_t)p * ND + i];
  __syncthreads();
  const float4* br = (const float4*)(B + (size_t)v * ND);
  float s = 0.f;
#pragma unroll 4
  for (int i = 0; i < ND / 4; ++i) {
    float4 b = br[i];
    const float4 a = *(const float4*)&arow[i * 4];
    float d0 = a.x - b.x, d1 = a.y - b.y, d2 = a.z - b.z, d3 = a.w - b.w;
    s += d0 * d0 + d1 * d1 + d2 * d2 + d3 * d3;
  }
  unsigned long long pk = pack_sv(s, v);
#pragma unroll
  for (int msk = 1; msk < 64; msk <<= 1) {
    unsigned long long o = __shfl_xor(pk, msk);
    pk = (o < pk) ? o : pk;
  }
  if ((threadIdx.x & 63) == 0) atomicMin(&best[p], pk);
}

// Gather winning rows + ids (ids written as float, d_out is read as flat f32).
__global__ __launch_bounds__(128) void gather_k(const unsigned long long* __restrict__ best,
                                                const float* __restrict__ clip,
                                                float* __restrict__ out) {
  int p = blockIdx.x;
  unsigned long long pk = best[p];
  unsigned v = (unsigned)(pk & 0xffffffffull);
  const float4* src = (const float4*)(clip + (size_t)v * ND);
  float4* dst = (float4*)(out + (size_t)p * ND);
  dst[threadIdx.x] = src[threadIdx.x];
  if (threadIdx.x == 0) out[(size_t)NP * ND + p] = (float)v;
}

extern "C" void kernel_launch(void* const* d_in, const int* in_sizes, int n_in,
                              void* d_out, int out_size, void* d_ws, size_t ws_size,
                              hipStream_t stream) {
  const float* prompt = (const float*)d_in[0];
  const float* clip = (const float*)d_in[1];
  float* out = (float*)d_out;

  // workspace layout
  size_t off = 0;
  unsigned long long* best = (unsigned long long*)d_ws;
  off += (size_t)NP * 8;
  float* b2 = (float*)((char*)d_ws + off);
  off += (size_t)NV * 4;
  off = (off + 255) & ~(size_t)255;
  __bf16* Ap = (__bf16*)((char*)d_ws + off);
  off += (size_t)NP * 1024 * 2;                // 2 MiB  [hi|lo]
  __bf16* Bp = (__bf16*)((char*)d_ws + off);
  off += (size_t)NV * 1024 * 2;                // 96.5 MiB [hi|lo]
  const size_t need = off;

  if (ws_size >= need) {
    hipMemsetAsync(best, 0xFF, (size_t)NP * 8, stream);
    pack_rows_k<<<NP / 4, 256, 0, stream>>>(prompt, Ap, nullptr, NP);
    pack_rows_k<<<NV / 4, 256, 0, stream>>>(clip, Bp, b2, NV);
    gemm_argmin_k<<<dim3((NP / 256) * (NV / 256)), 512, 0, stream>>>(Ap, Bp, b2, best);
    gather_k<<<NP, 128, 0, stream>>>(best, clip, out);
  } else {
    // fallback: exact fp32, needs only the 8 KiB `best` array
    hipMemsetAsync(best, 0xFF, (size_t)NP * 8, stream);
    dim3 grid(NV / 256, NP);
    naive_argmin_k<<<grid, 256, 0, stream>>>(prompt, clip, best);
    gather_k<<<NP, 128, 0, stream>>>(best, clip, out);
  }
}

// Round 8
// 268.130 us; speedup vs baseline: 1.0112x; 1.0112x over previous
//
#include <hip/hip_runtime.h>
#include <stdint.h>

#define NP 1024
#define NV 49408
#define ND 512
// A,B packed: [row][hi(512)|lo(512)] bf16 -> physical K=1024 (2048 B/row).
// Logical K=1536, 3-term split, BK=64 -> 24 K-tiles:
//   t 0-7:  ah*bh   t 8-15: al*bh   t 16-23: ah*bl
//   A phys byte = (t & 15) * 128
//   B phys byte = ((t & 7) + (t >= 16 ? 8 : 0)) * 128
#define NT 24
#define NI 12

typedef __attribute__((ext_vector_type(8))) __bf16 bf16x8;
typedef __attribute__((ext_vector_type(4))) float f32x4;
typedef __attribute__((ext_vector_type(4))) int i32x4;

__device__ inline unsigned long long pack_sv(float s, unsigned v) {
  unsigned u = __float_as_uint(s);
  u = (u & 0x80000000u) ? ~u : (u | 0x80000000u);  // orderable map
  return ((unsigned long long)u << 32) | (unsigned long long)v;
}

// Split each f32 row into bf16 hi/lo halves, layout [row][hi(512)|lo(512)];
// optionally emit exact f32 sum of squares per row.
__global__ __launch_bounds__(256) void pack_rows_k(const float* __restrict__ src,
                                                   __bf16* __restrict__ dst,
                                                   float* __restrict__ sumsq,
                                                   int nrows) {
  int lane = threadIdx.x & 63;
  int row = blockIdx.x * 4 + (threadIdx.x >> 6);
  if (row >= nrows) return;
  const float* r = src + (size_t)row * ND + lane * 8;
  float4 x0 = *(const float4*)r;
  float4 x1 = *(const float4*)(r + 4);
  float xs[8] = {x0.x, x0.y, x0.z, x0.w, x1.x, x1.y, x1.z, x1.w};
  bf16x8 hi, lo;
  float ss = 0.f;
#pragma unroll
  for (int j = 0; j < 8; ++j) {
    float x = xs[j];
    ss += x * x;
    __bf16 h = (__bf16)x;
    hi[j] = h;
    lo[j] = (__bf16)(x - (float)h);   // exact residual, then RTNE to bf16
  }
  __bf16* drow = dst + (size_t)row * 1024 + lane * 8;
  *(bf16x8*)drow = hi;
  *(bf16x8*)(drow + 512) = lo;
  if (sumsq != nullptr) {
#pragma unroll
    for (int m = 1; m < 64; m <<= 1) ss += __shfl_xor(ss, m);
    if (lane == 0) sumsq[row] = ss;
  }
}

// ---- 256x256, BK=64, 8-wave (2Mx4N), 8-phase dbuf pipeline (m201-style) ----
// LDS 128 KiB: buf b at b*65536: A row-half h (128 rows x 64 k-cols bf16,
// 16 KB) at +h*16384; B col-half h at +32768+h*16384. Row = 128 B = 8 x 16B
// slots; LDS slot s of row r holds global k-slot s^(r&7) (involution).
// Stage: linear LDS dest + inverse-swizzled global source (rule #21).
// Fragment reads are inline-asm ds_read_b128 (invisible to alias analysis ->
// no compiler-inserted vmcnt guard against in-flight global_load_lds) with
// explicit lgkmcnt(0)+sched_barrier(0) before the MFMA cluster (rule #18).

__device__ __attribute__((always_inline)) static inline
void gll16(const char* src, char* dst) {
  __builtin_amdgcn_global_load_lds(
      (const __attribute__((address_space(1))) void*)src,
      (__attribute__((address_space(3))) void*)dst, 16, 0, 0);
}

// one half-tile = 128 rows x 128 B; thread covers rows tid>>3 and +64
__device__ __attribute__((always_inline)) static inline
void stage_half(const char* src, char* dst) {
  gll16(src, dst);
  gll16(src + 131072, dst + 8192);
}

__device__ __attribute__((always_inline)) static inline
bf16x8 lds_read(unsigned addr) {
  i32x4 d;
  asm volatile("ds_read_b128 %0, %1" : "=v"(d) : "v"(addr));
  return __builtin_bit_cast(bf16x8, d);
}

__device__ __attribute__((always_inline)) static inline
void read_a(bf16x8 (&a)[4][2], unsigned k0, unsigned k1, int off) {
#pragma unroll
  for (int mm = 0; mm < 4; ++mm) {
    a[mm][0] = lds_read(k0 + off + mm * 2048);
    a[mm][1] = lds_read(k1 + off + mm * 2048);
  }
}

__device__ __attribute__((always_inline)) static inline
void read_b(bf16x8 (&b)[2][2], unsigned k0, unsigned k1, int off) {
#pragma unroll
  for (int nn = 0; nn < 2; ++nn) {
    b[nn][0] = lds_read(k0 + off + nn * 2048);
    b[nn][1] = lds_read(k1 + off + nn * 2048);
  }
}

template <int MB, int NB>
__device__ __attribute__((always_inline)) static inline
void mfma16(f32x4 (&acc)[8][4], const bf16x8 (&a)[4][2], const bf16x8 (&b)[2][2]) {
  __builtin_amdgcn_s_setprio(1);
#pragma unroll
  for (int mm = 0; mm < 4; ++mm)
#pragma unroll
    for (int nn = 0; nn < 2; ++nn)
#pragma unroll
      for (int kk = 0; kk < 2; ++kk)
        acc[MB + mm][NB + nn] = __builtin_amdgcn_mfma_f32_16x16x32_bf16(
            a[mm][kk], b[nn][kk], acc[MB + mm][NB + nn], 0, 0, 0);
  __builtin_amdgcn_s_setprio(0);
}

#define FENCE asm volatile("" ::: "memory")
#define BAR1  do { FENCE; __builtin_amdgcn_s_barrier(); FENCE; } while (0)
#define ENDP  do { FENCE; __builtin_amdgcn_s_barrier(); FENCE; } while (0)
#define VMC4  asm volatile("s_waitcnt vmcnt(4)" ::: "memory")
#define LGKM0 do { asm volatile("s_waitcnt lgkmcnt(0)" ::: "memory"); \
                   __builtin_amdgcn_sched_barrier(0); } while (0)

__global__ __launch_bounds__(512, 2) void gemm_argmin_k(const __bf16* __restrict__ A,
                                                        const __bf16* __restrict__ B,
                                                        const float* __restrict__ b2,
                                                        unsigned long long* __restrict__ best) {
  __shared__ __align__(128) char lds[131072];
  const int tid = threadIdx.x;
  const int lane = tid & 63;
  const int wid = tid >> 6;   // 0..7
  const int wm = wid >> 2;    // 2 wave-rows (128 rows each)
  const int wn = wid & 3;     // 4 wave-cols (64 cols each)

  // bijective XCD-chunk swizzle, nwg = 772 = 8*96 + 4 (m204 formula):
  const int d = blockIdx.x;
  const int xcd = d & 7;
  const int wg = (xcd < 4 ? xcd * 97 : 388 + (xcd - 4) * 96) + (d >> 3);
  const int bm = (wg & 3) * 256;   // 4 M-blocks per B-panel, same XCD
  const int bn = (wg >> 2) * 256;

  const int r = lane & 15, g = lane >> 4;
  const int sl = (g ^ (r & 7)) * 16;
  const int offA = wm * 16384 + r * 128 + sl;
  const int offB = 32768 + (wn >> 1) * 16384 + (wn & 1) * 8192 + r * 128 + sl;

  const unsigned lds0 =
      (unsigned)(uintptr_t)(const __attribute__((address_space(3))) char*)(const char*)lds;
  const unsigned aK0b0 = lds0 + offA;
  const unsigned aK1b0 = aK0b0 ^ 64;          // k-half 1: slot ^= 4
  const unsigned aK0b1 = aK0b0 + 65536;
  const unsigned aK1b1 = aK0b1 ^ 64;
  const unsigned bK0b0 = lds0 + offB;
  const unsigned bK1b0 = bK0b0 ^ 64;
  const unsigned bK0b1 = bK0b0 + 65536;
  const unsigned bK1b1 = bK0b1 ^ 64;

  // stage side: thread covers row tid>>3 (+64 / +128-half), slot (tid&7),
  // inverse-swizzled global column slot:
  const int srow = tid >> 3;
  const int sc = (tid & 7) ^ (srow & 7);
  const char* srcA = (const char*)A + (size_t)(bm + srow) * 2048 + sc * 16;
  const char* srcB = (const char*)B + (size_t)(bn + srow) * 2048 + sc * 16;
  char* st = (char*)lds + tid * 16;

  f32x4 acc[8][4] = {};
  bf16x8 a[4][2], b0v[2][2], b1v[2][2];

  auto aByte = [](int t) { return (t & 15) * 128; };
  auto bByte = [](int t) { return ((t & 7) + (t >= 16 ? 8 : 0)) * 128; };

  // prologue: buf0 all 4 halves (tile 0) + buf1 B halves (tile 1)
  stage_half(srcA + aByte(0),          st + 0);        // b0.A0
  stage_half(srcA + aByte(0) + 262144, st + 16384);    // b0.A1
  stage_half(srcB + bByte(0),          st + 32768);    // b0.B0
  stage_half(srcB + bByte(0) + 262144, st + 49152);    // b0.B1
  stage_half(srcB + bByte(1),          st + 98304);    // b1.B0
  stage_half(srcB + bByte(1) + 262144, st + 114688);   // b1.B1
  VMC4;            // buf0 fully resident; buf1.B in flight
  BAR1;

  // per iter: T0=2it (buf0), T1=2it+1 (buf1); stages:
  //  P1:b1.A0(T1) P2:b1.A1(T1) P3:b0.B0(T0+2) P4:b0.B1 [vmcnt4]
  //  P5:b0.A0(T0+2) P6:b0.A1 P7:b1.B0(T1+2) P8:b1.B1 [vmcnt4]
#pragma unroll 1
  for (int it = 0; it < NI; ++it) {
    const int T1 = 2 * it + 1;
    int S0 = 2 * it + 2; if (S0 >= NT) S0 -= NT;   // tail wrap: dead re-stage
    int S1 = 2 * it + 3; if (S1 >= NT) S1 -= NT;
    // P1 (buf0, quad m0n0)
    read_a(a, aK0b0, aK1b0, 0);
    read_b(b0v, bK0b0, bK1b0, 0);
    stage_half(srcA + aByte(T1), st + 65536);
    BAR1; LGKM0; mfma16<0, 0>(acc, a, b0v); ENDP;
    // P2 (m0n1)
    read_b(b1v, bK0b0, bK1b0, 4096);
    stage_half(srcA + aByte(T1) + 262144, st + 81920);
    BAR1; LGKM0; mfma16<0, 2>(acc, a, b1v); ENDP;
    // P3 (m1n1)
    read_a(a, aK0b0, aK1b0, 8192);
    stage_half(srcB + bByte(S0), st + 32768);
    BAR1; LGKM0; mfma16<4, 2>(acc, a, b1v); ENDP;
    // P4 (m1n0)  [no reads]
    stage_half(srcB + bByte(S0) + 262144, st + 49152);
    BAR1; mfma16<4, 0>(acc, a, b0v); VMC4; ENDP;
    // P5 (buf1, m0n0)
    read_a(a, aK0b1, aK1b1, 0);
    read_b(b0v, bK0b1, bK1b1, 0);
    stage_half(srcA + aByte(S0), st + 0);
    BAR1; LGKM0; mfma16<0, 0>(acc, a, b0v); ENDP;
    // P6 (m0n1)
    read_b(b1v, bK0b1, bK1b1, 4096);
    stage_half(srcA + aByte(S0) + 262144, st + 16384);
    BAR1; LGKM0; mfma16<0, 2>(acc, a, b1v); ENDP;
    // P7 (m1n1)
    read_a(a, aK0b1, aK1b1, 8192);
    stage_half(srcB + bByte(S1), st + 98304);
    BAR1; LGKM0; mfma16<4, 2>(acc, a, b1v); ENDP;
    // P8 (m1n0)
    stage_half(srcB + bByte(S1) + 262144, st + 114688);
    BAR1; mfma16<4, 0>(acc, a, b0v); VMC4; ENDP;
  }

  // epilogue: fused argmin. C/D map: col = lane&15, row = (lane>>4)*4 + reg.
  float bb[4];
#pragma unroll
  for (int n = 0; n < 4; ++n) bb[n] = b2[bn + wn * 64 + n * 16 + r];
#pragma unroll
  for (int m = 0; m < 8; ++m) {
#pragma unroll
    for (int reg = 0; reg < 4; ++reg) {
      unsigned long long pk = ~0ull;
#pragma unroll
      for (int n = 0; n < 4; ++n) {
        float s = bb[n] - 2.0f * acc[m][n][reg];
        unsigned long long cand = pack_sv(s, (unsigned)(bn + wn * 64 + n * 16 + r));
        pk = (cand < pk) ? cand : pk;
      }
#pragma unroll
      for (int msk = 1; msk < 16; msk <<= 1) {
        unsigned long long o = __shfl_xor(pk, msk);
        pk = (o < pk) ? o : pk;
      }
      if (r == 0) atomicMin(&best[bm + wm * 128 + m * 16 + g * 4 + reg], pk);
    }
  }
}

// Fallback (small ws): exact fp32 squared distance, fused argmin.
__global__ __launch_bounds__(256) void naive_argmin_k(const float* __restrict__ A,
                                                      const float* __restrict__ B,
                                                      unsigned long long* __restrict__ best) {
  __shared__ float arow[ND];
  int p = blockIdx.y;
  unsigned v = blockIdx.x * 256 + threadIdx.x;
  for (int i = threadIdx.x; i < ND; i += 256) arow[i] = A[(size_t)p * ND + i];
  __syncthreads();
  const float4* br = (const float4*)(B + (size_t)v * ND);
  float s = 0.f;
#pragma unroll 4
  for (int i = 0; i < ND / 4; ++i) {
    float4 b = br[i];
    const float4 a = *(const float4*)&arow[i * 4];
    float d0 = a.x - b.x, d1 = a.y - b.y, d2 = a.z - b.z, d3 = a.w - b.w;
    s += d0 * d0 + d1 * d1 + d2 * d2 + d3 * d3;
  }
  unsigned long long pk = pack_sv(s, v);
#pragma unroll
  for (int msk = 1; msk < 64; msk <<= 1) {
    unsigned long long o = __shfl_xor(pk, msk);
    pk = (o < pk) ? o : pk;
  }
  if ((threadIdx.x & 63) == 0) atomicMin(&best[p], pk);
}

// Gather winning rows + ids (ids written as float, d_out is read as flat f32).
__global__ __launch_bounds__(128) void gather_k(const unsigned long long* __restrict__ best,
                                                const float* __restrict__ clip,
                                                float* __restrict__ out) {
  int p = blockIdx.x;
  unsigned long long pk = best[p];
  unsigned v = (unsigned)(pk & 0xffffffffull);
  const float4* src = (const float4*)(clip + (size_t)v * ND);
  float4* dst = (float4*)(out + (size_t)p * ND);
  dst[threadIdx.x] = src[threadIdx.x];
  if (threadIdx.x == 0) out[(size_t)NP * ND + p] = (float)v;
}

extern "C" void kernel_launch(void* const* d_in, const int* in_sizes, int n_in,
                              void* d_out, int out_size, void* d_ws, size_t ws_size,
                              hipStream_t stream) {
  const float* prompt = (const float*)d_in[0];
  const float* clip = (const float*)d_in[1];
  float* out = (float*)d_out;

  // workspace layout
  size_t off = 0;
  unsigned long long* best = (unsigned long long*)d_ws;
  off += (size_t)NP * 8;
  float* b2 = (float*)((char*)d_ws + off);
  off += (size_t)NV * 4;
  off = (off + 255) & ~(size_t)255;
  __bf16* Ap = (__bf16*)((char*)d_ws + off);
  off += (size_t)NP * 1024 * 2;                // 2 MiB  [hi|lo]
  __bf16* Bp = (__bf16*)((char*)d_ws + off);
  off += (size_t)NV * 1024 * 2;                // 96.5 MiB [hi|lo]
  const size_t need = off;

  if (ws_size >= need) {
    hipMemsetAsync(best, 0xFF, (size_t)NP * 8, stream);
    pack_rows_k<<<NP / 4, 256, 0, stream>>>(prompt, Ap, nullptr, NP);
    pack_rows_k<<<NV / 4, 256, 0, stream>>>(clip, Bp, b2, NV);
    gemm_argmin_k<<<dim3((NP / 256) * (NV / 256)), 512, 0, stream>>>(Ap, Bp, b2, best);
    gather_k<<<NP, 128, 0, stream>>>(best, clip, out);
  } else {
    // fallback: exact fp32, needs only the 8 KiB `best` array
    hipMemsetAsync(best, 0xFF, (size_t)NP * 8, stream);
    dim3 grid(NV / 256, NP);
    naive_argmin_k<<<grid, 256, 0, stream>>>(prompt, clip, best);
    gather_k<<<NP, 128, 0, stream>>>(best, clip, out);
  }
}